// Round 6
// baseline (142.963 us; speedup 1.0000x reference)
//
#include <hip/hip_runtime.h>
#include <math.h>

// Problem constants
#define NTOK 16384
#define DDIM 4096
#define NEXP 64
#define KTOP 4

// GEMM config
#define SPLITK 8
#define KPER (DDIM / SPLITK)   // 512 k per split (interleaved chunks)
#define BK 32                  // k per chunk (one 16x16x32 MFMA k-step)
#define NCH (KPER / BK)        // 16 chunks per split
#define BMB 256                // tokens per block = 8 waves x 32 rows

typedef __attribute__((ext_vector_type(8))) short short8;
typedef __attribute__((ext_vector_type(4))) float f32x4;

// ws layout:
//   part [NTOK][SPLITK][NEXP] f32 = 32 MB
//   Whi  [NEXP][DDIM] ushort      = 512 KB
//   Wlo  [NEXP][DDIM] ushort      = 512 KB

__device__ __forceinline__ unsigned short f2bf_rtn(float x) {
    unsigned int b = __float_as_uint(x);
    return (unsigned short)((b + 0x7FFFu + ((b >> 16) & 1u)) >> 16);
}
__device__ __forceinline__ float bf2f(unsigned short h) {
    return __uint_as_float(((unsigned int)h) << 16);
}

// ---------------- Kernel 1: split W into bf16 hi/lo, zero counts -------------
__global__ __launch_bounds__(256) void prep_kernel(
    const float* __restrict__ W, unsigned short* __restrict__ Whi,
    unsigned short* __restrict__ Wlo, float* __restrict__ counts)
{
    int idx = blockIdx.x * 256 + threadIdx.x;   // 0 .. 64*4096
    float x = W[idx];
    unsigned short h = f2bf_rtn(x);
    float lo = x - bf2f(h);
    Whi[idx] = h;
    Wlo[idx] = f2bf_rtn(lo);
    if (blockIdx.x == 0 && threadIdx.x < NEXP) counts[threadIdx.x] = 0.0f;
}

// ---------------- Kernel 2: bf16x3-split MFMA GEMM, W-slice in LDS -----------
// 512 blocks x 512 threads (8 waves), 1 block/CU (128 KB LDS).
// INTERLEAVED split-K: split s owns global chunks {c*8+s, c=0..15} -> per-split
// k-window spans the full 16 KB row (HBM channel-bit spread). Per-wave XOR
// chunk-phase staggers concurrent k across waves. Depth-3 A prefetch.
__global__ __launch_bounds__(512, 2) void gemm_kernel(
    const float* __restrict__ X, const unsigned short* __restrict__ Whi,
    const unsigned short* __restrict__ Wlo, float* __restrict__ part)
{
    __shared__ unsigned short sHi[NEXP * KPER];   // 64 KB
    __shared__ unsigned short sLo[NEXP * KPER];   // 64 KB

    const int tid  = threadIdx.x;
    const int lane = tid & 63;
    const int w    = tid >> 6;                 // wave 0..7
    const int tb   = blockIdx.x >> 3;          // token block 0..63
    const int s    = blockIdx.x & 7;           // k-split    0..7
    const int tok0 = tb * BMB + w * 32;        // this wave's first row

    // ---- stage W slice (interleaved chunks): thread t = (e = t>>3, j = t&7) --
    // LDS local short-offset kk = j*8 + i*64  (chunk c = kk>>5, within o = kk&31)
    // global short-offset     = (kk>>5)*256 + s*32 + (kk&31)
    {
        const int e = tid >> 3;
        const int j = tid & 7;
        const size_t gbase = (size_t)e * DDIM + s * 32 + (j & 3) * 8 + (j >> 2) * 256;
        const unsigned short* gh = Whi + gbase;
        const unsigned short* gl = Wlo + gbase;
        const int m = (e & 7) * 8;             // XOR swizzle (ushort units)
        #pragma unroll
        for (int i = 0; i < 8; ++i) {
            const int kk = j * 8 + i * 64;
            short8 vh = *(const short8*)(gh + i * 512);
            short8 vl = *(const short8*)(gl + i * 512);
            *(short8*)&sHi[e * KPER + (kk ^ m)] = vh;
            *(short8*)&sLo[e * KPER + (kk ^ m)] = vl;
        }
    }
    __syncthreads();

    const int fr = lane & 15;                  // fragment row (token) / col (expert)
    const int fg = lane >> 4;                  // k subgroup 0..3

    // per-wave chunk phase (bijective XOR walk; de-correlates k across waves)
    const int phase = ((w << 1) | (tb & 1)) & 15;
    const int p256  = phase << 8;                       // float units, A side
    const int kxp   = (phase << 5) ^ (fg * 8) ^ ((fr & 7) * 8);  // short units, LDS side

    // A bases: row tok0 + mg*16 + fr; local chunk c -> global float offset
    //   ((c^phase)*256) + s*32 + fg*8   [(c*256)^(p256) == (c^phase)*256]
    const float* __restrict__ xa0 = X + (size_t)(tok0 + fr) * DDIM + s * 32 + fg * 8;
    const float* __restrict__ xa1 = xa0 + (size_t)16 * DDIM;

    f32x4 acc[2][4];
    #pragma unroll
    for (int mg = 0; mg < 2; ++mg)
        #pragma unroll
        for (int ng = 0; ng < 4; ++ng)
            acc[mg][ng] = (f32x4){0.f, 0.f, 0.f, 0.f};

    // A pipeline buffers, fully unrolled (static indices -> SSA registers)
    float4 xq[NCH][2][2];

#define LOADA(c)                                                            \
    {                                                                       \
        const int fo = ((c) * 256) ^ p256;                                  \
        xq[c][0][0] = *(const float4*)(xa0 + fo);                           \
        xq[c][0][1] = *(const float4*)(xa0 + fo + 4);                       \
        xq[c][1][0] = *(const float4*)(xa1 + fo);                           \
        xq[c][1][1] = *(const float4*)(xa1 + fo + 4);                       \
    }

    LOADA(0)
    LOADA(1)
    LOADA(2)

    #pragma unroll
    for (int c = 0; c < NCH; ++c) {
        if (c + 3 < NCH) LOADA(c + 3)          // depth-3 prefetch

        // ---- split A fp32 -> bf16 hi/lo fragments ----
        short8 ahi[2], alo[2];
        #pragma unroll
        for (int mg = 0; mg < 2; ++mg) {
            #pragma unroll
            for (int j = 0; j < 8; ++j) {
                const float4 q = xq[c][mg][j >> 2];
                float xv = ((j & 3) == 0) ? q.x : ((j & 3) == 1) ? q.y
                         : ((j & 3) == 2) ? q.z : q.w;
                unsigned short h = f2bf_rtn(xv);
                float lo = xv - bf2f(h);
                ahi[mg][j] = (short)h;
                alo[mg][j] = (short)(__float_as_uint(lo) >> 16);   // RTZ lo
            }
        }

        // ---- B from LDS (swizzled, phase-consistent) + 24 MFMAs ----
        #pragma unroll
        for (int ng = 0; ng < 4; ++ng) {
            const int bE = (ng * 16 + fr) * KPER;
            const int t  = (c * BK) ^ kxp;     // == ((c^phase)*BK) ^ swizzle
            const short8 bh = *(const short8*)(sHi + bE + t);
            const short8 bl = *(const short8*)(sLo + bE + t);
            #pragma unroll
            for (int mg = 0; mg < 2; ++mg) {
                acc[mg][ng] = __builtin_amdgcn_mfma_f32_16x16x32_bf16(
                    ahi[mg], bh, acc[mg][ng], 0, 0, 0);
                acc[mg][ng] = __builtin_amdgcn_mfma_f32_16x16x32_bf16(
                    ahi[mg], bl, acc[mg][ng], 0, 0, 0);
                acc[mg][ng] = __builtin_amdgcn_mfma_f32_16x16x32_bf16(
                    alo[mg], bh, acc[mg][ng], 0, 0, 0);
            }
        }
    }
#undef LOADA

    // ---- store partials [n][s][e] (route reads 2 KB contiguous per token) ---
    // C/D layout: col = lane&15 (expert), row = fg*4 + reg (token)
    #pragma unroll
    for (int mg = 0; mg < 2; ++mg)
        #pragma unroll
        for (int r = 0; r < 4; ++r) {
            const int row = tok0 + mg * 16 + fg * 4 + r;
            float* __restrict__ pp = part + ((size_t)row * SPLITK + s) * NEXP;
            #pragma unroll
            for (int ng = 0; ng < 4; ++ng)
                pp[ng * 16 + fr] = acc[mg][ng][r];
        }
}

// ---------------- Kernel 3: softmax + group-limited top-k routing ------------
__global__ __launch_bounds__(256) void route_kernel(
    const float* __restrict__ part, float* __restrict__ outW,
    float* __restrict__ outI, float* __restrict__ counts)
{
    __shared__ int hist[NEXP];
    const int tid = threadIdx.x;
    if (tid < NEXP) hist[tid] = 0;
    __syncthreads();

    const int lane = tid & 63;
    const int wv   = tid >> 6;   // wave 0..3
    const int tok_base = blockIdx.x * 32 + wv * 8;

    for (int t = 0; t < 8; ++t) {
        const int n = tok_base + t;
        // sum split-K partials (layout [n][s][e]): 2 KB contiguous per token
        float L = 0.0f;
        #pragma unroll
        for (int s = 0; s < SPLITK; ++s)
            L += part[((size_t)n * SPLITK + s) * NEXP + lane];

        // softmax over 64 experts (wave = expert axis)
        float m = L;
        #pragma unroll
        for (int off = 32; off > 0; off >>= 1) m = fmaxf(m, __shfl_xor(m, off));
        float p = expf(L - m);
        float ssum = p;
        #pragma unroll
        for (int off = 32; off > 0; off >>= 1) ssum += __shfl_xor(ssum, off);
        float score = p / ssum;

        // group max within each 8-lane group
        float gm = score;
        gm = fmaxf(gm, __shfl_xor(gm, 1));
        gm = fmaxf(gm, __shfl_xor(gm, 2));
        gm = fmaxf(gm, __shfl_xor(gm, 4));

        // gather all 8 group maxima, serial top-4 groups (ties -> lower index)
        float ga[8];
        #pragma unroll
        for (int g = 0; g < 8; ++g) ga[g] = __shfl(gm, g * 8);
        unsigned selmask = 0u;
        #pragma unroll
        for (int r = 0; r < 4; ++r) {
            float best = -INFINITY; int bg = 0;
            #pragma unroll
            for (int g = 0; g < 8; ++g) {
                bool taken  = (selmask >> g) & 1u;
                bool better = (!taken) && (ga[g] > best);
                bg   = better ? g : bg;
                best = better ? ga[g] : best;
            }
            selmask |= (1u << bg);
        }

        // mask non-selected groups, wave-wide top-4 (ties -> lower idx)
        float ms = ((selmask >> (lane >> 3)) & 1u) ? score : -INFINITY;
        float wk[4]; int wi[4];
        #pragma unroll
        for (int r = 0; r < 4; ++r) {
            float v = ms; int ix = lane;
            #pragma unroll
            for (int off = 32; off > 0; off >>= 1) {
                float vo = __shfl_xor(v, off);
                int   io = __shfl_xor(ix, off);
                if (vo > v || (vo == v && io < ix)) { v = vo; ix = io; }
            }
            wk[r] = v; wi[r] = ix;
            if (lane == ix) ms = -INFINITY;
        }

        if (lane == 0) {
            *(float4*)&outW[(size_t)n * 4] = make_float4(wk[0], wk[1], wk[2], wk[3]);
            *(float4*)&outI[(size_t)n * 4] =
                make_float4((float)wi[0], (float)wi[1], (float)wi[2], (float)wi[3]);
            atomicAdd(&hist[wi[0]], 1);
            atomicAdd(&hist[wi[1]], 1);
            atomicAdd(&hist[wi[2]], 1);
            atomicAdd(&hist[wi[3]], 1);
        }
    }

    __syncthreads();
    if (tid < NEXP) atomicAdd(&counts[tid], (float)hist[tid]);
}

extern "C" void kernel_launch(void* const* d_in, const int* in_sizes, int n_in,
                              void* d_out, int out_size, void* d_ws, size_t ws_size,
                              hipStream_t stream) {
    const float* X = (const float*)d_in[0];
    const float* W = (const float*)d_in[1];

    float* outW   = (float*)d_out;                    // [N,4] weights
    float* outI   = outW + (size_t)NTOK * KTOP;       // [N,4] indices (as float)
    float* counts = outW + (size_t)2 * NTOK * KTOP;   // [64]  counts  (as float)

    float*          part = (float*)d_ws;                              // 32 MB
    unsigned short* Whi  = (unsigned short*)(part + (size_t)NTOK * SPLITK * NEXP);
    unsigned short* Wlo  = Whi + (size_t)NEXP * DDIM;

    prep_kernel<<<(NEXP * DDIM) / 256, 256, 0, stream>>>(W, Whi, Wlo, counts);
    gemm_kernel<<<(NTOK / BMB) * SPLITK, 512, 0, stream>>>(X, Whi, Wlo, part);
    route_kernel<<<NTOK / 32, 256, 0, stream>>>(part, outW, outI, counts);
}

// Round 7
// 107.115 us; speedup vs baseline: 1.3347x; 1.3347x over previous
//
#include <hip/hip_runtime.h>
#include <math.h>

// Problem constants
#define NTOK 16384
#define DDIM 4096
#define NEXP 64
#define KTOP 4

// GEMM config
#define SPLITK 8
#define KPER (DDIM / SPLITK)   // 512 k per split
#define BK 32                  // k per chunk (one 16x16x32 MFMA k-step)
#define NCH (KPER / BK)        // 16 chunks
#define BMB 256                // tokens per block = 8 waves x 32 rows

typedef __attribute__((ext_vector_type(8))) short short8;
typedef __attribute__((ext_vector_type(4))) float f32x4;

// ws layout:
//   part [NTOK][SPLITK][NEXP] f32 = 32 MB
//   Whi  [NEXP][DDIM] ushort      = 512 KB
//   Wlo  [NEXP][DDIM] ushort      = 512 KB

__device__ __forceinline__ unsigned short f2bf_rtn(float x) {
    unsigned int b = __float_as_uint(x);
    return (unsigned short)((b + 0x7FFFu + ((b >> 16) & 1u)) >> 16);
}
__device__ __forceinline__ float bf2f(unsigned short h) {
    return __uint_as_float(((unsigned int)h) << 16);
}

__device__ __forceinline__ short8 mk8(unsigned int a, unsigned int b,
                                      unsigned int c, unsigned int d) {
    union { unsigned int u[4]; short8 s; } p;
    p.u[0] = a; p.u[1] = b; p.u[2] = c; p.u[3] = d;
    return p.s;
}

// ---------------- Kernel 1: split W into bf16 hi/lo (RTN), zero counts -------
__global__ __launch_bounds__(256) void prep_kernel(
    const float* __restrict__ W, unsigned short* __restrict__ Whi,
    unsigned short* __restrict__ Wlo, float* __restrict__ counts)
{
    int idx = blockIdx.x * 256 + threadIdx.x;   // 0 .. 64*4096
    float x = W[idx];
    unsigned short h = f2bf_rtn(x);
    float lo = x - bf2f(h);
    Whi[idx] = h;
    Wlo[idx] = f2bf_rtn(lo);
    if (blockIdx.x == 0 && threadIdx.x < NEXP) counts[threadIdx.x] = 0.0f;
}

// ---------------- Kernel 2: bf16x3-split MFMA GEMM, W-slice in LDS -----------
// 512 blocks x 512 threads (8 waves), 1 resident block/CU (128 KB LDS).
// Block = 256 tokens x 64 experts x KPER k.  X read exactly once device-wide.
// Blocked split-K (compile-time immediate-offset A addressing), depth-4 A
// prefetch, RTZ hi/lo split (packed uint ops), wave-synchronous LDS reads.
__global__ __launch_bounds__(512, 2) void gemm_kernel(
    const float* __restrict__ X, const unsigned short* __restrict__ Whi,
    const unsigned short* __restrict__ Wlo, float* __restrict__ part)
{
    __shared__ unsigned short sHi[NEXP * KPER];   // 64 KB
    __shared__ unsigned short sLo[NEXP * KPER];   // 64 KB

    const int tid  = threadIdx.x;
    const int lane = tid & 63;
    const int w    = tid >> 6;                 // wave 0..7
    const int tb   = blockIdx.x >> 3;          // token block 0..63
    const int s    = blockIdx.x & 7;           // k-split    0..7
    const int kbase = s * KPER;
    const int tok0 = tb * BMB + w * 32;        // this wave's first row

    const int fr = lane & 15;                  // fragment row (token) / col (expert)
    const int fg = lane >> 4;                  // k subgroup 0..3
    const int kx = (fg * 8) ^ ((fr & 7) * 8);  // swizzled per-lane k offset (shorts)

    // A bases: row tok0 + mg*16 + fr, k = kbase + c*32 + fg*8 (imm offsets per c)
    const float* __restrict__ xa0 = X + (size_t)(tok0 + fr) * DDIM + kbase + fg * 8;
    const float* __restrict__ xa1 = xa0 + (size_t)16 * DDIM;

    // ---- stage W slice: thread t covers expert e=t>>3, pieces j=t&7 (+64i) --
    {
        const int e = tid >> 3;
        const int j = tid & 7;
        const unsigned short* gh = Whi + (size_t)e * DDIM + kbase + j * 8;
        const unsigned short* gl = Wlo + (size_t)e * DDIM + kbase + j * 8;
        const int m = (e & 7) * 8;             // XOR swizzle (ushort units)
        #pragma unroll
        for (int i = 0; i < 8; ++i) {
            const int kk = j * 8 + i * 64;
            short8 vh = *(const short8*)(gh + i * 64);
            short8 vl = *(const short8*)(gl + i * 64);
            *(short8*)&sHi[e * KPER + (kk ^ m)] = vh;
            *(short8*)&sLo[e * KPER + (kk ^ m)] = vl;
        }
    }

    // A pipeline buffers, fully unrolled (static indices -> SSA registers)
    float4 xq[NCH][2][2];

#define LOADA(c)                                                            \
    {                                                                       \
        xq[c][0][0] = *(const float4*)(xa0 + (c) * BK);                     \
        xq[c][0][1] = *(const float4*)(xa0 + (c) * BK + 4);                 \
        xq[c][1][0] = *(const float4*)(xa1 + (c) * BK);                     \
        xq[c][1][1] = *(const float4*)(xa1 + (c) * BK + 4);                 \
    }

    // issue first 4 chunks' A loads before the barrier (overlap with staging)
    LOADA(0)
    LOADA(1)
    LOADA(2)
    LOADA(3)

    __syncthreads();

    f32x4 acc[2][4];
    #pragma unroll
    for (int mg = 0; mg < 2; ++mg)
        #pragma unroll
        for (int ng = 0; ng < 4; ++ng)
            acc[mg][ng] = (f32x4){0.f, 0.f, 0.f, 0.f};

    #pragma unroll
    for (int c = 0; c < NCH; ++c) {
        if (c + 4 < NCH) LOADA(c + 4)          // depth-4 prefetch

        // ---- RTZ split A fp32 -> bf16 hi/lo fragments (packed uint ops) ----
        short8 ahi[2], alo[2];
        #pragma unroll
        for (int mg = 0; mg < 2; ++mg) {
            unsigned int hi[4], lo[4];
            #pragma unroll
            for (int h = 0; h < 2; ++h) {
                const float4 q = xq[c][mg][h];
                const unsigned int ux = __float_as_uint(q.x);
                const unsigned int uy = __float_as_uint(q.y);
                const unsigned int uz = __float_as_uint(q.z);
                const unsigned int uw = __float_as_uint(q.w);
                hi[h * 2]     = (ux >> 16) | (uy & 0xFFFF0000u);
                hi[h * 2 + 1] = (uz >> 16) | (uw & 0xFFFF0000u);
                const float lx = q.x - __uint_as_float(ux & 0xFFFF0000u);
                const float ly = q.y - __uint_as_float(uy & 0xFFFF0000u);
                const float lz = q.z - __uint_as_float(uz & 0xFFFF0000u);
                const float lw = q.w - __uint_as_float(uw & 0xFFFF0000u);
                lo[h * 2]     = (__float_as_uint(lx) >> 16) | (__float_as_uint(ly) & 0xFFFF0000u);
                lo[h * 2 + 1] = (__float_as_uint(lz) >> 16) | (__float_as_uint(lw) & 0xFFFF0000u);
            }
            ahi[mg] = mk8(hi[0], hi[1], hi[2], hi[3]);
            alo[mg] = mk8(lo[0], lo[1], lo[2], lo[3]);
        }

        // ---- B from LDS (swizzled broadcast) + 24 MFMAs ----
        #pragma unroll
        for (int ng = 0; ng < 4; ++ng) {
            const int bE = (ng * 16 + fr) * KPER;
            const int t  = (c * BK) ^ kx;      // c*BK compile-time under unroll
            const short8 bh = *(const short8*)(sHi + bE + t);
            const short8 bl = *(const short8*)(sLo + bE + t);
            #pragma unroll
            for (int mg = 0; mg < 2; ++mg) {
                acc[mg][ng] = __builtin_amdgcn_mfma_f32_16x16x32_bf16(
                    ahi[mg], bh, acc[mg][ng], 0, 0, 0);
                acc[mg][ng] = __builtin_amdgcn_mfma_f32_16x16x32_bf16(
                    ahi[mg], bl, acc[mg][ng], 0, 0, 0);
                acc[mg][ng] = __builtin_amdgcn_mfma_f32_16x16x32_bf16(
                    alo[mg], bh, acc[mg][ng], 0, 0, 0);
            }
        }
    }
#undef LOADA

    // ---- store partials [n][s][e] (route reads 2 KB contiguous per token) ---
    // C/D layout: col = lane&15 (expert), row = fg*4 + reg (token)
    #pragma unroll
    for (int mg = 0; mg < 2; ++mg)
        #pragma unroll
        for (int r = 0; r < 4; ++r) {
            const int row = tok0 + mg * 16 + fg * 4 + r;
            float* __restrict__ pp = part + ((size_t)row * SPLITK + s) * NEXP;
            #pragma unroll
            for (int ng = 0; ng < 4; ++ng)
                pp[ng * 16 + fr] = acc[mg][ng][r];
        }
}

// ---------------- Kernel 3: softmax + group-limited top-k routing ------------
__global__ __launch_bounds__(256) void route_kernel(
    const float* __restrict__ part, float* __restrict__ outW,
    float* __restrict__ outI, float* __restrict__ counts)
{
    __shared__ int hist[NEXP];
    const int tid = threadIdx.x;
    if (tid < NEXP) hist[tid] = 0;
    __syncthreads();

    const int lane = tid & 63;
    const int wv   = tid >> 6;   // wave 0..3
    const int tok_base = blockIdx.x * 32 + wv * 8;

    for (int t = 0; t < 8; ++t) {
        const int n = tok_base + t;
        // sum split-K partials (layout [n][s][e]): 2 KB contiguous per token
        float L = 0.0f;
        #pragma unroll
        for (int s = 0; s < SPLITK; ++s)
            L += part[((size_t)n * SPLITK + s) * NEXP + lane];

        // softmax over 64 experts (wave = expert axis)
        float m = L;
        #pragma unroll
        for (int off = 32; off > 0; off >>= 1) m = fmaxf(m, __shfl_xor(m, off));
        float p = expf(L - m);
        float ssum = p;
        #pragma unroll
        for (int off = 32; off > 0; off >>= 1) ssum += __shfl_xor(ssum, off);
        float score = p / ssum;

        // group max within each 8-lane group
        float gm = score;
        gm = fmaxf(gm, __shfl_xor(gm, 1));
        gm = fmaxf(gm, __shfl_xor(gm, 2));
        gm = fmaxf(gm, __shfl_xor(gm, 4));

        // gather all 8 group maxima, serial top-4 groups (ties -> lower index)
        float ga[8];
        #pragma unroll
        for (int g = 0; g < 8; ++g) ga[g] = __shfl(gm, g * 8);
        unsigned selmask = 0u;
        #pragma unroll
        for (int r = 0; r < 4; ++r) {
            float best = -INFINITY; int bg = 0;
            #pragma unroll
            for (int g = 0; g < 8; ++g) {
                bool taken  = (selmask >> g) & 1u;
                bool better = (!taken) && (ga[g] > best);
                bg   = better ? g : bg;
                best = better ? ga[g] : best;
            }
            selmask |= (1u << bg);
        }

        // mask non-selected groups, wave-wide top-4 (ties -> lower idx)
        float ms = ((selmask >> (lane >> 3)) & 1u) ? score : -INFINITY;
        float wk[4]; int wi[4];
        #pragma unroll
        for (int r = 0; r < 4; ++r) {
            float v = ms; int ix = lane;
            #pragma unroll
            for (int off = 32; off > 0; off >>= 1) {
                float vo = __shfl_xor(v, off);
                int   io = __shfl_xor(ix, off);
                if (vo > v || (vo == v && io < ix)) { v = vo; ix = io; }
            }
            wk[r] = v; wi[r] = ix;
            if (lane == ix) ms = -INFINITY;
        }

        if (lane == 0) {
            *(float4*)&outW[(size_t)n * 4] = make_float4(wk[0], wk[1], wk[2], wk[3]);
            *(float4*)&outI[(size_t)n * 4] =
                make_float4((float)wi[0], (float)wi[1], (float)wi[2], (float)wi[3]);
            atomicAdd(&hist[wi[0]], 1);
            atomicAdd(&hist[wi[1]], 1);
            atomicAdd(&hist[wi[2]], 1);
            atomicAdd(&hist[wi[3]], 1);
        }
    }

    __syncthreads();
    if (tid < NEXP) atomicAdd(&counts[tid], (float)hist[tid]);
}

extern "C" void kernel_launch(void* const* d_in, const int* in_sizes, int n_in,
                              void* d_out, int out_size, void* d_ws, size_t ws_size,
                              hipStream_t stream) {
    const float* X = (const float*)d_in[0];
    const float* W = (const float*)d_in[1];

    float* outW   = (float*)d_out;                    // [N,4] weights
    float* outI   = outW + (size_t)NTOK * KTOP;       // [N,4] indices (as float)
    float* counts = outW + (size_t)2 * NTOK * KTOP;   // [64]  counts  (as float)

    float*          part = (float*)d_ws;                              // 32 MB
    unsigned short* Whi  = (unsigned short*)(part + (size_t)NTOK * SPLITK * NEXP);
    unsigned short* Wlo  = Whi + (size_t)NEXP * DDIM;

    prep_kernel<<<(NEXP * DDIM) / 256, 256, 0, stream>>>(W, Whi, Wlo, counts);
    gemm_kernel<<<(NTOK / BMB) * SPLITK, 512, 0, stream>>>(X, Whi, Wlo, part);
    route_kernel<<<NTOK / 32, 256, 0, stream>>>(part, outW, outI, counts);
}